// Round 4
// baseline (228.013 us; speedup 1.0000x reference)
//
#include <hip/hip_runtime.h>
#include <math.h>

// Problem constants
#define BB    16
#define TT    2048
#define VOCAB 14
#define TOKD  8
#define POSD  8
#define DM    16      // TOKD + POSD
#define NH    2
#define HD    3
#define AD    6       // NH*HD
#define FFND  3

#define NTOK  (BB*TT)            // 32768
#define BH    (BB*NH)            // 32
#define QPW   64                 // queries per wave (1 per lane)
#define QB2   (TT/QPW)           // 32 query blocks per bh
#define CKA   256                // keys per chunk
#define CMAX  (TT/CKA)           // 8 chunk slots
#define WSLOT (BH*QB2*CMAX)      // 8192 wave slots
#define NBLK  (WSLOT/4)          // 2048 blocks

// ---------------------------------------------------------------------------
// Kernel 1: per-token prep. Gather+concat -> store pre-LN x; LN1; Q/K/V
// matvecs; Q prescaled by log2e/sqrt(3); KV packed 32B records; zero-init
// attention accumulator {a0,a1,a2,l} per (token,head).
// ---------------------------------------------------------------------------
__global__ __launch_bounds__(256) void prep_kernel(
    const int* __restrict__ idx,
    const float* __restrict__ tok_emb,
    const float* __restrict__ pos_enc,
    const float* __restrict__ Wq,
    const float* __restrict__ Wk,
    const float* __restrict__ Wv,
    const float* __restrict__ ln1w,
    const float* __restrict__ ln1b,
    float* __restrict__ xbuf,
    float* __restrict__ qbuf,
    float* __restrict__ kvbuf,
    float* __restrict__ abuf)
{
    int gid = blockIdx.x * blockDim.x + threadIdx.x;
    if (gid >= NTOK) return;
    int t = gid & (TT - 1);
    int b = gid >> 11;

    // zero the attention accumulator (2 heads x {a0,a1,a2,l})
    float4 z4 = make_float4(0.f, 0.f, 0.f, 0.f);
    *(float4*)(abuf + (size_t)gid * 8)     = z4;
    *(float4*)(abuf + (size_t)gid * 8 + 4) = z4;

    float x[DM];
    int tok = idx[gid];
    #pragma unroll
    for (int j = 0; j < TOKD; ++j) x[j]        = tok_emb[tok * TOKD + j];
    #pragma unroll
    for (int j = 0; j < POSD; ++j) x[TOKD + j] = pos_enc[t * POSD + j];

    float* xp = xbuf + (size_t)gid * DM;
    #pragma unroll
    for (int j = 0; j < DM; j += 4)
        *(float4*)(xp + j) = make_float4(x[j], x[j+1], x[j+2], x[j+3]);

    // LN1
    float m = 0.f;
    #pragma unroll
    for (int j = 0; j < DM; ++j) m += x[j];
    m *= (1.f / DM);
    float v = 0.f;
    #pragma unroll
    for (int j = 0; j < DM; ++j) { float d = x[j] - m; v += d * d; }
    v *= (1.f / DM);
    float rs = rsqrtf(v + 1e-5f);
    float h[DM];
    #pragma unroll
    for (int j = 0; j < DM; ++j)
        h[j] = (x[j] - m) * rs * ln1w[j] + ln1b[j];

    float q[AD], k[AD], vv[AD];
    #pragma unroll
    for (int a = 0; a < AD; ++a) {
        float sq = 0.f, sk = 0.f, sv = 0.f;
        #pragma unroll
        for (int j = 0; j < 8; ++j) {
            sq = fmaf(Wq[a * 8 + j], h[TOKD + j], sq);
            sk = fmaf(Wk[a * 8 + j], h[TOKD + j], sk);
            sv = fmaf(Wv[a * 8 + j], h[j], sv);
        }
        q[a] = sq; k[a] = sk; vv[a] = sv;
    }

    const float QS = 1.4426950408889634f / 1.7320508075688772f; // log2(e)/sqrt(HD)
    #pragma unroll
    for (int hh = 0; hh < NH; ++hh) {
        size_t base = (size_t)(b * NH + hh) * TT + t;
        *(float4*)(qbuf + base * 4) =
            make_float4(q[hh*3] * QS, q[hh*3+1] * QS, q[hh*3+2] * QS, 0.f);
        *(float4*)(kvbuf + base * 8) =
            make_float4(k[hh*3], k[hh*3+1], k[hh*3+2], 0.f);
        *(float4*)(kvbuf + base * 8 + 4) =
            make_float4(vv[hh*3], vv[hh*3+1], vv[hh*3+2], 0.f);
    }
}

// ---------------------------------------------------------------------------
// Kernel 2: causal attention, lane-per-query. Wave = (bh, 64-query block,
// 256-key chunk). Key stream is wave-uniform -> scalar-cache loads (or at
// worst 1-cacheline uniform vector loads) -- no per-lane address divergence.
// Each lane privately accumulates (l,a) for its query; causal mask only on
// the diagonal chunk; partials combined via global f32 atomics.
// ---------------------------------------------------------------------------
__global__ __launch_bounds__(256) void attn_kernel(
    const float* __restrict__ qbuf,
    const float* __restrict__ kvbuf,
    float* __restrict__ abuf)
{
    int w   = blockIdx.x * 4 + (threadIdx.x >> 6);
    int bh  = w >> 8;                        // / (QB2*CMAX)
    int rem = w & 255;
    int qb  = rem >> 3;                      // query block 0..31
    int ck  = rem & 7;                       // chunk slot 0..7

    int nch = (qb >> 2) + 1;                 // chunks needed = ceil((i0+64)/256)
    if (ck >= nch) return;                   // wave-uniform exit

    int lane = threadIdx.x & 63;
    int i0   = qb << 6;
    int iq   = i0 + lane;                    // this lane's query row
    int kb   = ck << 8;                      // chunk's first key

    const float4 qv = *(const float4*)(qbuf + ((size_t)bh * TT + iq) * 4);
    const float q0 = qv.x, q1 = qv.y, q2 = qv.z;

    const float4* kvp = (const float4*)(kvbuf + ((size_t)bh * TT + kb) * 8);

    float l = 0.f, a0 = 0.f, a1 = 0.f, a2 = 0.f;

    // unmasked keys: t in [kb, min(kb+CKA, i0))
    int nun = min(CKA, i0 - kb);             // kb <= i0 always for active waves
    #pragma unroll 4
    for (int it = 0; it < nun; ++it) {
        float4 kk = kvp[2 * it];
        float4 vz = kvp[2 * it + 1];
        float s = fmaf(q0, kk.x, fmaf(q1, kk.y, q2 * kk.z));
        float p = exp2f(s);
        l  += p;
        a0 = fmaf(p, vz.x, a0);
        a1 = fmaf(p, vz.y, a1);
        a2 = fmaf(p, vz.z, a2);
    }

    // diagonal (masked) keys: t in [kb+nun, min(kb+CKA, i0+64))
    int kend = min(kb + CKA, i0 + QPW);
    for (int t = kb + nun; t < kend; ++t) {
        float4 kk = kvp[2 * (t - kb)];
        float4 vz = kvp[2 * (t - kb) + 1];
        float s = fmaf(q0, kk.x, fmaf(q1, kk.y, q2 * kk.z));
        float p = exp2f(s);
        p = (t <= iq) ? p : 0.f;
        l  += p;
        a0 = fmaf(p, vz.x, a0);
        a1 = fmaf(p, vz.y, a1);
        a2 = fmaf(p, vz.z, a2);
    }

    int b = bh >> 1, head = bh & 1;
    float* op = abuf + (((size_t)(b * TT + iq)) * NH + head) * 4;
    atomicAdd(op + 0, a0);
    atomicAdd(op + 1, a1);
    atomicAdd(op + 2, a2);
    atomicAdd(op + 3, l);
}

// ---------------------------------------------------------------------------
// Kernel 3: per-token epilogue. Normalize attention partials, Wo+residual,
// LN2, exact GELU FFN, residual, LNf, logits (16->8->14), f32 store.
// ---------------------------------------------------------------------------
__device__ __forceinline__ void layernorm16(
    const float* in, float* out, const float* w, const float* bsh)
{
    float m = 0.f;
    #pragma unroll
    for (int j = 0; j < DM; ++j) m += in[j];
    m *= (1.f / DM);
    float v = 0.f;
    #pragma unroll
    for (int j = 0; j < DM; ++j) { float d = in[j] - m; v += d * d; }
    v *= (1.f / DM);
    float rs = rsqrtf(v + 1e-5f);
    #pragma unroll
    for (int j = 0; j < DM; ++j)
        out[j] = (in[j] - m) * rs * w[j] + bsh[j];
}

__global__ __launch_bounds__(256) void epi_kernel(
    const float* __restrict__ xbuf,
    const float* __restrict__ abuf,
    const float* __restrict__ Wo,
    const float* __restrict__ ln2w,
    const float* __restrict__ ln2b,
    const float* __restrict__ lnfw,
    const float* __restrict__ lnfb,
    const float* __restrict__ W1,
    const float* __restrict__ b1,
    const float* __restrict__ W2,
    const float* __restrict__ b2,
    const float* __restrict__ Wh,
    const float* __restrict__ tok_emb,
    float* __restrict__ out)
{
    int gid = blockIdx.x * blockDim.x + threadIdx.x;
    if (gid >= NTOK) return;

    float x[DM];
    const float* xp = xbuf + (size_t)gid * DM;
    #pragma unroll
    for (int j = 0; j < DM; ++j) x[j] = xp[j];

    // normalize attention partials
    float att[AD];
    #pragma unroll
    for (int hh = 0; hh < NH; ++hh) {
        float4 p = *(const float4*)(abuf + ((size_t)gid * NH + hh) * 4);
        float inv = 1.f / p.w;
        att[hh*3+0] = p.x * inv;
        att[hh*3+1] = p.y * inv;
        att[hh*3+2] = p.z * inv;
    }

    // x += att @ Wo.T
    float xo[DM];
    #pragma unroll
    for (int j = 0; j < DM; ++j) {
        float s = x[j];
        #pragma unroll
        for (int a = 0; a < AD; ++a) s = fmaf(Wo[j * AD + a], att[a], s);
        xo[j] = s;
    }

    // LN2 -> FFN (exact gelu) -> residual
    float h2[DM];
    layernorm16(xo, h2, ln2w, ln2b);
    float g[FFND];
    #pragma unroll
    for (int c = 0; c < FFND; ++c) {
        float f = b1[c];
        #pragma unroll
        for (int j = 0; j < DM; ++j) f = fmaf(W1[c * DM + j], h2[j], f);
        g[c] = 0.5f * f * (1.f + erff(f * 0.70710678118654752f));
    }
    float x2[DM];
    #pragma unroll
    for (int j = 0; j < DM; ++j) {
        float s = xo[j] + b2[j];
        #pragma unroll
        for (int c = 0; c < FFND; ++c) s = fmaf(W2[j * FFND + c], g[c], s);
        x2[j] = s;
    }

    // LNf -> logits
    float y[DM];
    layernorm16(x2, y, lnfw, lnfb);
    float t8[TOKD];
    #pragma unroll
    for (int p = 0; p < TOKD; ++p) {
        float s = 0.f;
        #pragma unroll
        for (int j = 0; j < DM; ++j) s = fmaf(Wh[p * DM + j], y[j], s);
        t8[p] = s;
    }
    float* op = out + (size_t)gid * VOCAB;
    #pragma unroll
    for (int vcb = 0; vcb < VOCAB; ++vcb) {
        float s = 0.f;
        #pragma unroll
        for (int p = 0; p < TOKD; ++p) s = fmaf(t8[p], tok_emb[vcb * TOKD + p], s);
        op[vcb] = s;
    }
}

// ---------------------------------------------------------------------------
extern "C" void kernel_launch(void* const* d_in, const int* in_sizes, int n_in,
                              void* d_out, int out_size, void* d_ws, size_t ws_size,
                              hipStream_t stream) {
    const int*   idx     = (const int*)d_in[0];
    const float* tok_emb = (const float*)d_in[1];
    const float* pos_enc = (const float*)d_in[2];
    const float* Wq      = (const float*)d_in[3];
    const float* Wk      = (const float*)d_in[4];
    const float* Wv      = (const float*)d_in[5];
    const float* Wo      = (const float*)d_in[6];
    const float* ln1w    = (const float*)d_in[7];
    const float* ln1b    = (const float*)d_in[8];
    const float* ln2w    = (const float*)d_in[9];
    const float* ln2b    = (const float*)d_in[10];
    const float* lnfw    = (const float*)d_in[11];
    const float* lnfb    = (const float*)d_in[12];
    const float* W1      = (const float*)d_in[13];
    const float* b1      = (const float*)d_in[14];
    const float* W2      = (const float*)d_in[15];
    const float* b2      = (const float*)d_in[16];
    const float* Wh      = (const float*)d_in[17];
    float* out = (float*)d_out;

    float* xbuf  = (float*)d_ws;                         // NTOK*16 = 524288 f
    float* qbuf  = xbuf  + (size_t)NTOK * DM;            // BH*T*4  = 262144 f
    float* kvbuf = qbuf  + (size_t)BH * TT * 4;          // BH*T*8  = 524288 f
    float* abuf  = kvbuf + (size_t)BH * TT * 8;          // NTOK*8  = 262144 f

    prep_kernel<<<NTOK / 256, 256, 0, stream>>>(
        idx, tok_emb, pos_enc, Wq, Wk, Wv, ln1w, ln1b, xbuf, qbuf, kvbuf, abuf);

    attn_kernel<<<NBLK, 256, 0, stream>>>(qbuf, kvbuf, abuf);

    epi_kernel<<<NTOK / 256, 256, 0, stream>>>(
        xbuf, abuf, Wo, ln2w, ln2b, lnfw, lnfb, W1, b1, W2, b2, Wh, tok_emb, out);
}

// Round 5
// 172.486 us; speedup vs baseline: 1.3219x; 1.3219x over previous
//
#include <hip/hip_runtime.h>
#include <math.h>

// Problem constants
#define BB    16
#define TT    2048
#define VOCAB 14
#define TOKD  8
#define POSD  8
#define DM    16      // TOKD + POSD
#define NH    2
#define HD    3
#define AD    6       // NH*HD
#define FFND  3

#define NTOK  (BB*TT)            // 32768
#define BH    (BB*NH)            // 32
#define QSUP  256                // queries per block (4 waves x 64)
#define CHK   128                // keys per chunk (LDS-staged)
#define RPB   72                 // chunk-blocks per bh: sum_{s=0..7} 2(s+1)
#define NBLK  (BH*RPB)           // 2304 blocks, all equal cost

// ---------------------------------------------------------------------------
// Kernel 1: per-token prep. Gather+concat -> store pre-LN x; LN1; Q/K/V
// matvecs; Q prescaled by log2e/sqrt(3); KV packed 32B records; zero-init
// attention accumulator {a0,a1,a2,l} per (token,head).
// ---------------------------------------------------------------------------
__global__ __launch_bounds__(128) void prep_kernel(
    const int* __restrict__ idx,
    const float* __restrict__ tok_emb,
    const float* __restrict__ pos_enc,
    const float* __restrict__ Wq,
    const float* __restrict__ Wk,
    const float* __restrict__ Wv,
    const float* __restrict__ ln1w,
    const float* __restrict__ ln1b,
    float* __restrict__ xbuf,
    float* __restrict__ qbuf,
    float* __restrict__ kvbuf,
    float* __restrict__ abuf)
{
    int gid = blockIdx.x * blockDim.x + threadIdx.x;
    if (gid >= NTOK) return;
    int t = gid & (TT - 1);
    int b = gid >> 11;

    // zero the attention accumulator (2 heads x {a0,a1,a2,l})
    float4 z4 = make_float4(0.f, 0.f, 0.f, 0.f);
    *(float4*)(abuf + (size_t)gid * 8)     = z4;
    *(float4*)(abuf + (size_t)gid * 8 + 4) = z4;

    float x[DM];
    int tok = idx[gid];
    #pragma unroll
    for (int j = 0; j < TOKD; ++j) x[j]        = tok_emb[tok * TOKD + j];
    #pragma unroll
    for (int j = 0; j < POSD; ++j) x[TOKD + j] = pos_enc[t * POSD + j];

    float* xp = xbuf + (size_t)gid * DM;
    #pragma unroll
    for (int j = 0; j < DM; j += 4)
        *(float4*)(xp + j) = make_float4(x[j], x[j+1], x[j+2], x[j+3]);

    // LN1
    float m = 0.f;
    #pragma unroll
    for (int j = 0; j < DM; ++j) m += x[j];
    m *= (1.f / DM);
    float v = 0.f;
    #pragma unroll
    for (int j = 0; j < DM; ++j) { float d = x[j] - m; v += d * d; }
    v *= (1.f / DM);
    float rs = rsqrtf(v + 1e-5f);
    float h[DM];
    #pragma unroll
    for (int j = 0; j < DM; ++j)
        h[j] = (x[j] - m) * rs * ln1w[j] + ln1b[j];

    float q[AD], k[AD], vv[AD];
    #pragma unroll
    for (int a = 0; a < AD; ++a) {
        float sq = 0.f, sk = 0.f, sv = 0.f;
        #pragma unroll
        for (int j = 0; j < 8; ++j) {
            sq = fmaf(Wq[a * 8 + j], h[TOKD + j], sq);
            sk = fmaf(Wk[a * 8 + j], h[TOKD + j], sk);
            sv = fmaf(Wv[a * 8 + j], h[j], sv);
        }
        q[a] = sq; k[a] = sk; vv[a] = sv;
    }

    const float QS = 1.4426950408889634f / 1.7320508075688772f; // log2(e)/sqrt(HD)
    #pragma unroll
    for (int hh = 0; hh < NH; ++hh) {
        size_t base = (size_t)(b * NH + hh) * TT + t;
        *(float4*)(qbuf + base * 4) =
            make_float4(q[hh*3] * QS, q[hh*3+1] * QS, q[hh*3+2] * QS, 0.f);
        *(float4*)(kvbuf + base * 8) =
            make_float4(k[hh*3], k[hh*3+1], k[hh*3+2], 0.f);
        *(float4*)(kvbuf + base * 8 + 4) =
            make_float4(vv[hh*3], vv[hh*3+1], vv[hh*3+2], 0.f);
    }
}

// ---------------------------------------------------------------------------
// Kernel 2: causal attention, LDS-staged split-K. Block = (bh, 256-query
// super-row s, 128-key chunk c); all 2304 blocks have identical cost.
// Chunk staged to LDS once (1 coalesced float4/thread); inner loop is
// 2 broadcast ds_read_b128 + ~8 VALU per key. Lane = query. Partials
// (linear, no max-shift) combined via global f32 atomics.
// ---------------------------------------------------------------------------
__global__ __launch_bounds__(256) void attn_kernel(
    const float* __restrict__ qbuf,
    const float* __restrict__ kvbuf,
    float* __restrict__ abuf)
{
    __shared__ float4 skv[2 * CHK];          // 128 records x 32B = 4KB

    int g  = blockIdx.x;
    int bh = g & (BH - 1);
    int r  = g >> 5;                         // 0..71
    int s  = 0;                              // super-row: s(s+1) <= r < (s+1)(s+2)
    while ((s + 1) * (s + 2) <= r) ++s;
    int c  = r - s * (s + 1);                // chunk slot 0..2s+1
    int kb = c << 7;                         // chunk's first key

    // stage chunk into LDS (256 float4 = 128 records)
    const float4* gkv = (const float4*)(kvbuf + ((size_t)bh * TT + kb) * 8);
    skv[threadIdx.x] = gkv[threadIdx.x];
    __syncthreads();

    int wv   = threadIdx.x >> 6;
    int lane = threadIdx.x & 63;
    int i0w  = (s << 8) + (wv << 6);         // wave's first query row
    if (kb > i0w + 63) return;               // chunk entirely above diagonal

    int iq = i0w + lane;
    const float4 qv = *(const float4*)(qbuf + ((size_t)bh * TT + iq) * 4);
    const float q0 = qv.x, q1 = qv.y, q2 = qv.z;

    float l = 0.f, a0 = 0.f, a1 = 0.f, a2 = 0.f;

    // unmasked: it in [0, nun) where kb+it < i0w  (kb <= i0w for survivors)
    int nun = min(CHK, i0w - kb);
    #pragma unroll 4
    for (int it = 0; it < nun; ++it) {
        float4 kk = skv[2 * it];
        float4 vz = skv[2 * it + 1];
        float sc = fmaf(q0, kk.x, fmaf(q1, kk.y, q2 * kk.z));
        float p = exp2f(sc);
        l  += p;
        a0 = fmaf(p, vz.x, a0);
        a1 = fmaf(p, vz.y, a1);
        a2 = fmaf(p, vz.z, a2);
    }

    // diagonal (masked): it in [nun, itmax), mask t<=iq
    int itmax = min(CHK, i0w + 64 - kb);
    #pragma unroll 4
    for (int it = nun; it < itmax; ++it) {
        float4 kk = skv[2 * it];
        float4 vz = skv[2 * it + 1];
        float sc = fmaf(q0, kk.x, fmaf(q1, kk.y, q2 * kk.z));
        float p = exp2f(sc);
        p = (kb + it <= iq) ? p : 0.f;
        l  += p;
        a0 = fmaf(p, vz.x, a0);
        a1 = fmaf(p, vz.y, a1);
        a2 = fmaf(p, vz.z, a2);
    }

    int b = bh >> 1, head = bh & 1;
    float* op = abuf + (((size_t)(b * TT + iq)) * NH + head) * 4;
    atomicAdd(op + 0, a0);
    atomicAdd(op + 1, a1);
    atomicAdd(op + 2, a2);
    atomicAdd(op + 3, l);
}

// ---------------------------------------------------------------------------
// Kernel 3: per-token epilogue. Normalize attention partials, Wo+residual,
// LN2, exact GELU FFN, residual, LNf, logits (16->8->14), f32 store.
// ---------------------------------------------------------------------------
__device__ __forceinline__ void layernorm16(
    const float* in, float* out, const float* w, const float* bsh)
{
    float m = 0.f;
    #pragma unroll
    for (int j = 0; j < DM; ++j) m += in[j];
    m *= (1.f / DM);
    float v = 0.f;
    #pragma unroll
    for (int j = 0; j < DM; ++j) { float d = in[j] - m; v += d * d; }
    v *= (1.f / DM);
    float rs = rsqrtf(v + 1e-5f);
    #pragma unroll
    for (int j = 0; j < DM; ++j)
        out[j] = (in[j] - m) * rs * w[j] + bsh[j];
}

__global__ __launch_bounds__(128) void epi_kernel(
    const float* __restrict__ xbuf,
    const float* __restrict__ abuf,
    const float* __restrict__ Wo,
    const float* __restrict__ ln2w,
    const float* __restrict__ ln2b,
    const float* __restrict__ lnfw,
    const float* __restrict__ lnfb,
    const float* __restrict__ W1,
    const float* __restrict__ b1,
    const float* __restrict__ W2,
    const float* __restrict__ b2,
    const float* __restrict__ Wh,
    const float* __restrict__ tok_emb,
    float* __restrict__ out)
{
    int gid = blockIdx.x * blockDim.x + threadIdx.x;
    if (gid >= NTOK) return;

    float x[DM];
    const float* xp = xbuf + (size_t)gid * DM;
    #pragma unroll
    for (int j = 0; j < DM; ++j) x[j] = xp[j];

    // normalize attention partials
    float att[AD];
    #pragma unroll
    for (int hh = 0; hh < NH; ++hh) {
        float4 p = *(const float4*)(abuf + ((size_t)gid * NH + hh) * 4);
        float inv = 1.f / p.w;
        att[hh*3+0] = p.x * inv;
        att[hh*3+1] = p.y * inv;
        att[hh*3+2] = p.z * inv;
    }

    // x += att @ Wo.T
    float xo[DM];
    #pragma unroll
    for (int j = 0; j < DM; ++j) {
        float s = x[j];
        #pragma unroll
        for (int a = 0; a < AD; ++a) s = fmaf(Wo[j * AD + a], att[a], s);
        xo[j] = s;
    }

    // LN2 -> FFN (exact gelu) -> residual
    float h2[DM];
    layernorm16(xo, h2, ln2w, ln2b);
    float g[FFND];
    #pragma unroll
    for (int c = 0; c < FFND; ++c) {
        float f = b1[c];
        #pragma unroll
        for (int j = 0; j < DM; ++j) f = fmaf(W1[c * DM + j], h2[j], f);
        g[c] = 0.5f * f * (1.f + erff(f * 0.70710678118654752f));
    }
    float x2[DM];
    #pragma unroll
    for (int j = 0; j < DM; ++j) {
        float s = xo[j] + b2[j];
        #pragma unroll
        for (int c = 0; c < FFND; ++c) s = fmaf(W2[j * FFND + c], g[c], s);
        x2[j] = s;
    }

    // LNf -> logits
    float y[DM];
    layernorm16(x2, y, lnfw, lnfb);
    float t8[TOKD];
    #pragma unroll
    for (int p = 0; p < TOKD; ++p) {
        float s = 0.f;
        #pragma unroll
        for (int j = 0; j < DM; ++j) s = fmaf(Wh[p * DM + j], y[j], s);
        t8[p] = s;
    }
    float* op = out + (size_t)gid * VOCAB;
    #pragma unroll
    for (int vcb = 0; vcb < VOCAB; ++vcb) {
        float s = 0.f;
        #pragma unroll
        for (int p = 0; p < TOKD; ++p) s = fmaf(t8[p], tok_emb[vcb * TOKD + p], s);
        op[vcb] = s;
    }
}

// ---------------------------------------------------------------------------
extern "C" void kernel_launch(void* const* d_in, const int* in_sizes, int n_in,
                              void* d_out, int out_size, void* d_ws, size_t ws_size,
                              hipStream_t stream) {
    const int*   idx     = (const int*)d_in[0];
    const float* tok_emb = (const float*)d_in[1];
    const float* pos_enc = (const float*)d_in[2];
    const float* Wq      = (const float*)d_in[3];
    const float* Wk      = (const float*)d_in[4];
    const float* Wv      = (const float*)d_in[5];
    const float* Wo      = (const float*)d_in[6];
    const float* ln1w    = (const float*)d_in[7];
    const float* ln1b    = (const float*)d_in[8];
    const float* ln2w    = (const float*)d_in[9];
    const float* ln2b    = (const float*)d_in[10];
    const float* lnfw    = (const float*)d_in[11];
    const float* lnfb    = (const float*)d_in[12];
    const float* W1      = (const float*)d_in[13];
    const float* b1      = (const float*)d_in[14];
    const float* W2      = (const float*)d_in[15];
    const float* b2      = (const float*)d_in[16];
    const float* Wh      = (const float*)d_in[17];
    float* out = (float*)d_out;

    float* xbuf  = (float*)d_ws;                         // NTOK*16 = 524288 f
    float* qbuf  = xbuf  + (size_t)NTOK * DM;            // BH*T*4  = 262144 f
    float* kvbuf = qbuf  + (size_t)BH * TT * 4;          // BH*T*8  = 524288 f
    float* abuf  = kvbuf + (size_t)BH * TT * 8;          // NTOK*8  = 262144 f

    prep_kernel<<<NTOK / 128, 128, 0, stream>>>(
        idx, tok_emb, pos_enc, Wq, Wk, Wv, ln1w, ln1b, xbuf, qbuf, kvbuf, abuf);

    attn_kernel<<<NBLK, 256, 0, stream>>>(qbuf, kvbuf, abuf);

    epi_kernel<<<NTOK / 128, 128, 0, stream>>>(
        xbuf, abuf, Wo, ln2w, ln2b, lnfw, lnfb, W1, b1, W2, b2, Wh, tok_emb, out);
}